// Round 4
// baseline (800.804 us; speedup 1.0000x reference)
//
#include <hip/hip_runtime.h>

typedef unsigned short u16;
typedef unsigned int   u32;
typedef __attribute__((ext_vector_type(8))) short short8;
typedef __attribute__((ext_vector_type(4))) float float4v;

// ---------- helpers ----------
__device__ __forceinline__ float bf2f(u16 u){ union{u32 i; float f;} c; c.i = ((u32)u) << 16; return c.f; }
__device__ __forceinline__ float bflo(u32 u){ union{u32 i; float f;} c; c.i = u << 16; return c.f; }
__device__ __forceinline__ float bfhi(u32 u){ union{u32 i; float f;} c; c.i = u & 0xFFFF0000u; return c.f; }
__device__ __forceinline__ u16 f2bf(float f){
  union{float f; u32 i;} c; c.f = f; u32 x = c.i;
  return (u16)((x + 0x7FFFu + ((x >> 16) & 1u)) >> 16);   // RNE
}
__device__ __forceinline__ u32 pack2(float a, float b){ return (u32)f2bf(a) | ((u32)f2bf(b) << 16); }

// ---------- fp32 -> bf16 bulk convert ----------
__global__ void f32_to_bf16(const float* __restrict__ src, u16* __restrict__ dst, int n4)
{
  int stride = gridDim.x * 256;
  for (int i = blockIdx.x * 256 + threadIdx.x; i < n4; i += stride) {
    float4 v = ((const float4*)src)[i];
    ushort4 o; o.x = f2bf(v.x); o.y = f2bf(v.y); o.z = f2bf(v.z); o.w = f2bf(v.w);
    ((ushort4*)dst)[i] = o;
  }
}

// ---------- prep: Wqk = [wq_w; wk_w] rows as-is (B^T layout), bf16; bias fp32 ----------
__global__ void prep_qkw(const float* __restrict__ wq, const float* __restrict__ wk,
                         const float* __restrict__ wqb, const float* __restrict__ wkb,
                         u16* __restrict__ Wqk, float* __restrict__ biasQK)
{
  int t = blockIdx.x * 256 + threadIdx.x;
  int stride = gridDim.x * 256;
  for (int i = t; i < 294912; i += stride) {       // 1536*768/4
    float4 v = (i < 147456) ? ((const float4*)wq)[i] : ((const float4*)wk)[i - 147456];
    ushort4 o; o.x = f2bf(v.x); o.y = f2bf(v.y); o.z = f2bf(v.z); o.w = f2bf(v.w);
    ((ushort4*)Wqk)[i] = o;
  }
  if (t < 768) biasQK[t] = wqb[t];
  else if (t < 1536) biasQK[t] = wkb[t - 768];
}

// gcnT[l][o][d] = gcn[l][d][o], fp32 -> bf16
__global__ void prep_gcnT(const float* __restrict__ gcn, u16* __restrict__ gcnT)
{
  __shared__ float tile[32][33];
  int l = blockIdx.z;
  int d0 = blockIdx.y * 32, o0 = blockIdx.x * 32;
  int tx = threadIdx.x, ty = threadIdx.y;           // 32 x 8
  const float* src = gcn + (size_t)l * 589824;
  u16* dst = gcnT + (size_t)l * 589824;
  for (int i = 0; i < 32; i += 8) tile[ty + i][tx] = src[(size_t)(d0 + ty + i) * 768 + o0 + tx];
  __syncthreads();
  for (int i = 0; i < 32; i += 8) dst[(size_t)(o0 + ty + i) * 768 + d0 + tx] = f2bf(tile[tx][ty + i]);
}

// ---------- main GEMM: C[m][n] = sum_k A[m][k]*B[n][k] + bias[n] (bf16 in/out, f32 acc) ----------
__global__ void __launch_bounds__(256) gemm_bt(const u16* __restrict__ A, const u16* __restrict__ Bw,
                                               const float* __restrict__ bias, u16* __restrict__ C,
                                               int M, int N, int K)
{
  __shared__ __attribute__((aligned(16))) u16 As[128 * 32];
  __shared__ __attribute__((aligned(16))) u16 Bs[128 * 32];
  int tid = threadIdx.x, lane = tid & 63, wid = tid >> 6;
  int wm = wid >> 1, wn = wid & 1;
  size_t m0 = (size_t)blockIdx.x * 128, n0 = (size_t)blockIdx.y * 128;

  float4v acc[4][4];
  for (int r = 0; r < 4; r++) for (int c = 0; c < 4; c++) acc[r][c] = (float4v){0.f, 0.f, 0.f, 0.f};

  int srow = tid >> 2;            // 0..63
  int scol = (tid & 3) * 8;       // u16 col offset
  const u16* gA0 = A  + (m0 + srow)      * (size_t)K + scol;
  const u16* gA1 = A  + (m0 + srow + 64) * (size_t)K + scol;
  const u16* gB0 = Bw + (n0 + srow)      * (size_t)K + scol;
  const u16* gB1 = Bw + (n0 + srow + 64) * (size_t)K + scol;

  int l15 = lane & 15, q8 = (lane >> 4) * 8;

  for (int kt = 0; kt < K; kt += 32) {
    uint4 a0 = *(const uint4*)(gA0 + kt);
    uint4 a1 = *(const uint4*)(gA1 + kt);
    uint4 b0 = *(const uint4*)(gB0 + kt);
    uint4 b1 = *(const uint4*)(gB1 + kt);
    __syncthreads();
    ((uint4*)As)[tid]       = a0;
    ((uint4*)As)[tid + 256] = a1;
    ((uint4*)Bs)[tid]       = b0;
    ((uint4*)Bs)[tid + 256] = b1;
    __syncthreads();
    short8 af[4], bfr[4];
    for (int r = 0; r < 4; r++) af[r]  = *(const short8*)&As[(wm * 64 + r * 16 + l15) * 32 + q8];
    for (int c = 0; c < 4; c++) bfr[c] = *(const short8*)&Bs[(wn * 64 + c * 16 + l15) * 32 + q8];
    for (int r = 0; r < 4; r++)
      for (int c = 0; c < 4; c++)
        acc[r][c] = __builtin_amdgcn_mfma_f32_16x16x32_bf16(af[r], bfr[c], acc[r][c], 0, 0, 0);
  }

  int quad = lane >> 4;
  for (int c = 0; c < 4; c++) {
    int n = (int)n0 + wn * 64 + c * 16 + l15;
    float bv = bias ? bias[n] : 0.f;
    for (int r = 0; r < 4; r++) {
      size_t mbase = m0 + wm * 64 + r * 16 + quad * 4;
      for (int t = 0; t < 4; t++)
        C[(mbase + t) * (size_t)N + n] = f2bf(acc[r][c][t] + bv);
    }
  }
}

// ---------- batched dot + square + L1-normalize: adj[g][i][j] ----------
template<int NPAD>
__global__ void __launch_bounds__(256) dot_adj(const u16* __restrict__ QK, float* __restrict__ adj, int n)
{
  constexpr int CT = NPAD / 16;
  __shared__ __attribute__((aligned(16))) u16 As[NPAD * 32];
  __shared__ __attribute__((aligned(16))) u16 Bs[NPAD * 32];
  int g = blockIdx.x, tid = threadIdx.x, lane = tid & 63, wid = tid >> 6;

  float4v acc[CT];
  for (int c = 0; c < CT; c++) acc[c] = (float4v){0.f, 0.f, 0.f, 0.f};

  int row = tid >> 2, kq = tid & 3;
  for (int kt = 0; kt < 768; kt += 32) {
    uint4 va = {0,0,0,0}, vb = {0,0,0,0};
    if (tid < NPAD * 4 && row < n) {
      const u16* base = QK + ((size_t)g * n + row) * 1536 + kt + kq * 8;
      va = *(const uint4*)base;
      vb = *(const uint4*)(base + 768);
    }
    __syncthreads();
    if (tid < NPAD * 4) {
      ((uint4*)As)[tid] = va;
      ((uint4*)Bs)[tid] = vb;
    }
    __syncthreads();
    if (wid < CT) {
      int l15 = lane & 15, q8 = (lane >> 4) * 8;
      short8 a = *(const short8*)&As[(wid * 16 + l15) * 32 + q8];
      for (int ct = 0; ct < CT; ct++) {
        short8 b = *(const short8*)&Bs[(ct * 16 + l15) * 32 + q8];
        acc[ct] = __builtin_amdgcn_mfma_f32_16x16x32_bf16(a, b, acc[ct], 0, 0, 0);
      }
    }
  }

  if (wid < CT) {
    int quad = lane >> 4, l15 = lane & 15;
    float* adjg = adj + (size_t)g * NPAD * NPAD;
    float rs[4];
    for (int r = 0; r < 4; r++) {
      float s = 0.f;
      for (int ct = 0; ct < CT; ct++) { float v = acc[ct][r]; s += v * v; }
      s += __shfl_xor(s, 1); s += __shfl_xor(s, 2); s += __shfl_xor(s, 4); s += __shfl_xor(s, 8);
      rs[r] = 1.0f / fmaxf(s, 1e-12f);
    }
    for (int ct = 0; ct < CT; ct++)
      for (int r = 0; r < 4; r++) {
        float v = acc[ct][r];
        int rrow = wid * 16 + quad * 4 + r, col = ct * 16 + l15;
        adjg[(size_t)rrow * NPAD + col] = v * v * rs[r];
      }
  }
}

// ---------- fused adj@H + LayerNorm + ReLU -> bf16 (ln params fp32) ----------
__global__ void __launch_bounds__(384) adjH_ln(const float* __restrict__ adj, const u16* __restrict__ H,
                                               const float* __restrict__ lng, const float* __restrict__ lnb,
                                               u16* __restrict__ out, int n, int npad, int layer)
{
  __shared__ float adjr[4][64];
  __shared__ float red[6][4][2];
  __shared__ float bc[4][2];
  int g = blockIdx.x, i0 = blockIdx.y * 4;
  int tid = threadIdx.x, wid = tid >> 6, lane = tid & 63;

  for (int idx = tid; idx < 4 * npad; idx += 384) {
    int ii = idx / npad, j = idx - ii * npad;
    adjr[ii][j] = adj[((size_t)g * npad + (i0 + ii)) * npad + j];
  }
  __syncthreads();

  int d0 = tid * 2;
  float a0[4] = {0,0,0,0}, a1[4] = {0,0,0,0};
  const u32* hp = (const u32*)H + (size_t)g * n * 384 + tid;
  for (int j = 0; j < n; j++) {
    u32 u = hp[(size_t)j * 384];
    float h0 = bflo(u), h1 = bfhi(u);
    for (int ii = 0; ii < 4; ii++) { float a = adjr[ii][j]; a0[ii] += a * h0; a1[ii] += a * h1; }
  }

  for (int ii = 0; ii < 4; ii++) {
    float s = a0[ii] + a1[ii];
    float q = a0[ii] * a0[ii] + a1[ii] * a1[ii];
    for (int m = 1; m <= 32; m <<= 1) { s += __shfl_xor(s, m); q += __shfl_xor(q, m); }
    if (lane == 0) { red[wid][ii][0] = s; red[wid][ii][1] = q; }
  }
  __syncthreads();
  if (tid < 4) {
    float s = 0.f, q = 0.f;
    for (int w = 0; w < 6; w++) { s += red[w][tid][0]; q += red[w][tid][1]; }
    float mu = s * (1.f / 768.f);
    float var = q * (1.f / 768.f) - mu * mu;
    bc[tid][0] = mu; bc[tid][1] = rsqrtf(fmaxf(var, 0.f) + 1e-5f);
  }
  __syncthreads();

  float lg0 = lng[layer * 768 + d0], lg1 = lng[layer * 768 + d0 + 1];
  float lb0 = lnb[layer * 768 + d0], lb1 = lnb[layer * 768 + d0 + 1];
  for (int ii = 0; ii < 4; ii++) {
    int i = i0 + ii; if (i >= n) continue;
    float mu = bc[ii][0], rs = bc[ii][1];
    float v0 = fmaxf((a0[ii] - mu) * rs * lg0 + lb0, 0.f);
    float v1 = fmaxf((a1[ii] - mu) * rs * lg1 + lb1, 0.f);
    *(u32*)&out[((size_t)g * n + i) * 768 + d0] = pack2(v0, v1);
  }
}

// ---------- mean over nodes -> bf16 [G][768] ----------
__global__ void __launch_bounds__(384) mean_nodes(const u16* __restrict__ X, u16* __restrict__ out,
                                                  int n, float inv)
{
  int g = blockIdx.x, tid = threadIdx.x;
  const u32* p = (const u32*)X + (size_t)g * n * 384 + tid;
  float s0 = 0.f, s1 = 0.f;
  for (int j = 0; j < n; j++) { u32 u = p[(size_t)j * 384]; s0 += bflo(u); s1 += bfhi(u); }
  ((u32*)out)[(size_t)g * 384 + tid] = pack2(s0 * inv, s1 * inv);
}

// ---------- frame mean (bf16 in) + concat fgs (fp32) -> y fp32 (in d_out) ----------
__global__ void __launch_bounds__(384) frame_mean_concat(const u16* __restrict__ X2f,
                                                         const float* __restrict__ fgs, float* __restrict__ yout)
{
  int b = blockIdx.x, tid = threadIdx.x;
  const u32* p = (const u32*)X2f + (size_t)b * 32 * 384 + tid;
  float s0 = 0.f, s1 = 0.f;
  for (int j = 0; j < 32; j++) { u32 u = p[(size_t)j * 384]; s0 += bflo(u); s1 += bfhi(u); }
  int d0 = tid * 2;
  yout[(size_t)b * 1536 + d0]     = s0 * (1.f / 32.f);
  yout[(size_t)b * 1536 + d0 + 1] = s1 * (1.f / 32.f);
  yout[(size_t)b * 1536 + 768 + d0]     = fgs[(size_t)b * 768 + d0];
  yout[(size_t)b * 1536 + 768 + d0 + 1] = fgs[(size_t)b * 768 + d0 + 1];
}

// ---------- classifier head (all fp32) ----------
__global__ void __launch_bounds__(256) fc_head(const float* __restrict__ yout,
                                               const float* __restrict__ fc1w, const float* __restrict__ fc1b,
                                               const float* __restrict__ fc2w, const float* __restrict__ fc2b,
                                               float* __restrict__ logits)
{
  __shared__ float yrow[1536];
  __shared__ float hrow[768];
  int b = blockIdx.x, tid = threadIdx.x;
  const float* yp = yout + (size_t)b * 1536;
  for (int i = tid; i < 1536; i += 256) yrow[i] = yp[i];
  __syncthreads();
  for (int o = tid; o < 768; o += 256) {
    float acc = fc1b[o];
    const float4* wr = (const float4*)(fc1w + (size_t)o * 1536);
    for (int k4 = 0; k4 < 384; k4++) {
      float4 w = wr[k4];
      const float* y4 = &yrow[k4 * 4];
      acc += w.x * y4[0] + w.y * y4[1] + w.z * y4[2] + w.w * y4[3];
    }
    hrow[o] = fmaxf(acc, 0.f);
  }
  __syncthreads();
  for (int o = tid; o < 400; o += 256) {
    float acc = fc2b[o];
    const float4* wr = (const float4*)(fc2w + (size_t)o * 768);
    for (int k4 = 0; k4 < 192; k4++) {
      float4 w = wr[k4];
      const float* h4 = &hrow[k4 * 4];
      acc += w.x * h4[0] + w.y * h4[1] + w.z * h4[2] + w.w * h4[3];
    }
    logits[(size_t)b * 400 + o] = acc;
  }
}

// ---------- launch ----------
extern "C" void kernel_launch(void* const* d_in, const int* in_sizes, int n_in,
                              void* d_out, int out_size, void* d_ws, size_t ws_size,
                              hipStream_t stream) {
  const float* feats = (const float*)d_in[0];
  const float* fgs   = (const float*)d_in[1];
  const float* wq_w  = (const float*)d_in[3];
  const float* wq_b  = (const float*)d_in[4];
  const float* wk_w  = (const float*)d_in[5];
  const float* wk_b  = (const float*)d_in[6];
  const float* gcn_w = (const float*)d_in[7];
  const float* ln_g  = (const float*)d_in[8];
  const float* ln_b  = (const float*)d_in[9];
  const float* fc1_w = (const float*)d_in[10];
  const float* fc1_b = (const float*)d_in[11];
  const float* fc2_w = (const float*)d_in[12];
  const float* fc2_b = (const float*)d_in[13];
  float* out  = (float*)d_out;
  float* yout = out + 16 * 400;               // y region: [16][1536] fp32

  char* ws = (char*)d_ws;
  size_t off = 0;
  auto alloc = [&](size_t b){ size_t r = off; off = (off + b + 255) & ~(size_t)255; return r; };
  // persistent buffers (~47 MB)
  u16*  Fb     = (u16*) (ws + alloc((size_t)25600 * 768 * 2));   // feats as bf16
  u16*  Wqk    = (u16*) (ws + alloc((size_t)1536 * 768 * 2));
  u16*  gcnT   = (u16*) (ws + alloc((size_t)2 * 768 * 768 * 2));
  float* biasQK= (float*)(ws + alloc((size_t)1536 * 4));
  u16*  Xf     = (u16*) (ws + alloc((size_t)512 * 768 * 2));
  u16*  QKf    = (u16*) (ws + alloc((size_t)512 * 1536 * 2));
  u16*  Hf     = (u16*) (ws + alloc((size_t)512 * 768 * 2));
  u16*  X1f    = (u16*) (ws + alloc((size_t)512 * 768 * 2));
  u16*  X2f    = (u16*) (ws + alloc((size_t)512 * 768 * 2));
  float* adjF  = (float*)(ws + alloc((size_t)16 * 32 * 32 * 4));
  size_t base = off;

  // object-level chunk size by ws budget (ws_size constant -> graph-safe)
  auto need = [&](int GC){ return base + (size_t)GC * 50 * 1536 * 2 + 512 + (size_t)GC * 64 * 64 * 4 + 512; };
  int GC = 64;
  if (need(512) <= ws_size) GC = 512;
  else if (need(256) <= ws_size) GC = 256;
  else if (need(128) <= ws_size) GC = 128;
  int R = GC * 50;
  size_t off2 = base;
  auto alloc2 = [&](size_t b){ size_t r = off2; off2 = (off2 + b + 255) & ~(size_t)255; return r; };
  u16*  QKc  = (u16*) (ws + alloc2((size_t)R * 1536 * 2));
  float* adjO = (float*)(ws + alloc2((size_t)GC * 64 * 64 * 4));
  u16* Hc  = QKc;                        // [R][768] (QK dead after dot_adj)
  u16* X1c = QKc + (size_t)R * 768;
  u16* H2c = QKc;
  u16* X2c = QKc + (size_t)R * 768;

  // prep
  f32_to_bf16<<<4800, 256, 0, stream>>>(feats, Fb, 25600 * 768 / 4);
  prep_qkw<<<288, 256, 0, stream>>>(wq_w, wk_w, wq_b, wk_b, Wqk, biasQK);
  prep_gcnT<<<dim3(24, 24, 2), dim3(32, 8), 0, stream>>>(gcn_w, gcnT);

  // ---- object-level graph (512 graphs of n=50), chunked ----
  int nchunks = 512 / GC;
  for (int c = 0; c < nchunks; c++) {
    const u16* fc = Fb + (size_t)c * GC * 50 * 768;
    gemm_bt<<<dim3(R / 128, 12), 256, 0, stream>>>(fc, Wqk, biasQK, QKc, R, 1536, 768);
    dot_adj<64><<<GC, 256, 0, stream>>>(QKc, adjO, 50);
    gemm_bt<<<dim3(R / 128, 6), 256, 0, stream>>>(fc, gcnT, nullptr, Hc, R, 768, 768);
    adjH_ln<<<dim3(GC, 13), 384, 0, stream>>>(adjO, Hc, ln_g, ln_b, X1c, 50, 64, 0);
    gemm_bt<<<dim3(R / 128, 6), 256, 0, stream>>>(X1c, gcnT + (size_t)768 * 768, nullptr, H2c, R, 768, 768);
    adjH_ln<<<dim3(GC, 13), 384, 0, stream>>>(adjO, H2c, ln_g, ln_b, X2c, 50, 64, 1);
    mean_nodes<<<GC, 384, 0, stream>>>(X2c, Xf + (size_t)c * GC * 768, 50, 1.f / 50.f);
  }

  // ---- frame-level graph (16 graphs of n=32) ----
  gemm_bt<<<dim3(4, 12), 256, 0, stream>>>(Xf, Wqk, biasQK, QKf, 512, 1536, 768);
  dot_adj<32><<<16, 256, 0, stream>>>(QKf, adjF, 32);
  gemm_bt<<<dim3(4, 6), 256, 0, stream>>>(Xf, gcnT, nullptr, Hf, 512, 768, 768);
  adjH_ln<<<dim3(16, 8), 384, 0, stream>>>(adjF, Hf, ln_g, ln_b, X1f, 32, 32, 0);
  gemm_bt<<<dim3(4, 6), 256, 0, stream>>>(X1f, gcnT + (size_t)768 * 768, nullptr, Hf, 512, 768, 768);
  adjH_ln<<<dim3(16, 8), 384, 0, stream>>>(adjF, Hf, ln_g, ln_b, X2f, 32, 32, 1);

  // ---- head ----
  frame_mean_concat<<<16, 384, 0, stream>>>(X2f, fgs, yout);
  fc_head<<<16, 256, 0, stream>>>(yout, fc1_w, fc1_b, fc2_w, fc2_b, out);
}

// Round 5
// 632.315 us; speedup vs baseline: 1.2665x; 1.2665x over previous
//
#include <hip/hip_runtime.h>

typedef unsigned short u16;
typedef unsigned int   u32;
typedef __attribute__((ext_vector_type(8))) short short8;
typedef __attribute__((ext_vector_type(4))) float float4v;

// ---------- helpers ----------
__device__ __forceinline__ float bf2f(u16 u){ union{u32 i; float f;} c; c.i = ((u32)u) << 16; return c.f; }
__device__ __forceinline__ float bflo(u32 u){ union{u32 i; float f;} c; c.i = u << 16; return c.f; }
__device__ __forceinline__ float bfhi(u32 u){ union{u32 i; float f;} c; c.i = u & 0xFFFF0000u; return c.f; }
__device__ __forceinline__ u16 f2bf(float f){
  union{float f; u32 i;} c; c.f = f; u32 x = c.i;
  return (u16)((x + 0x7FFFu + ((x >> 16) & 1u)) >> 16);   // RNE
}
__device__ __forceinline__ u32 pack2(float a, float b){ return (u32)f2bf(a) | ((u32)f2bf(b) << 16); }

// ---------- fp32 -> bf16 bulk convert ----------
__global__ void f32_to_bf16(const float* __restrict__ src, u16* __restrict__ dst, int n4)
{
  int stride = gridDim.x * 256;
  for (int i = blockIdx.x * 256 + threadIdx.x; i < n4; i += stride) {
    float4 v = ((const float4*)src)[i];
    ushort4 o; o.x = f2bf(v.x); o.y = f2bf(v.y); o.z = f2bf(v.z); o.w = f2bf(v.w);
    ((ushort4*)dst)[i] = o;
  }
}

// ---------- prep: Wqk = [wq_w; wk_w] rows as-is (B^T layout), bf16; bias fp32 ----------
__global__ void prep_qkw(const float* __restrict__ wq, const float* __restrict__ wk,
                         const float* __restrict__ wqb, const float* __restrict__ wkb,
                         u16* __restrict__ Wqk, float* __restrict__ biasQK)
{
  int t = blockIdx.x * 256 + threadIdx.x;
  int stride = gridDim.x * 256;
  for (int i = t; i < 294912; i += stride) {       // 1536*768/4
    float4 v = (i < 147456) ? ((const float4*)wq)[i] : ((const float4*)wk)[i - 147456];
    ushort4 o; o.x = f2bf(v.x); o.y = f2bf(v.y); o.z = f2bf(v.z); o.w = f2bf(v.w);
    ((ushort4*)Wqk)[i] = o;
  }
  if (t < 768) biasQK[t] = wqb[t];
  else if (t < 1536) biasQK[t] = wkb[t - 768];
}

// gcnT[l][o][d] = gcn[l][d][o], fp32 -> bf16
__global__ void prep_gcnT(const float* __restrict__ gcn, u16* __restrict__ gcnT)
{
  __shared__ float tile[32][33];
  int l = blockIdx.z;
  int d0 = blockIdx.y * 32, o0 = blockIdx.x * 32;
  int tx = threadIdx.x, ty = threadIdx.y;           // 32 x 8
  const float* src = gcn + (size_t)l * 589824;
  u16* dst = gcnT + (size_t)l * 589824;
  for (int i = 0; i < 32; i += 8) tile[ty + i][tx] = src[(size_t)(d0 + ty + i) * 768 + o0 + tx];
  __syncthreads();
  for (int i = 0; i < 32; i += 8) dst[(size_t)(o0 + ty + i) * 768 + d0 + tx] = f2bf(tile[tx][ty + i]);
}

// ---------- main GEMM: C[m][n] = sum_k A[m][k]*B[n][k] + bias[n] (bf16 in/out, f32 acc) ----------
__global__ void __launch_bounds__(256) gemm_bt(const u16* __restrict__ A, const u16* __restrict__ Bw,
                                               const float* __restrict__ bias, u16* __restrict__ C,
                                               int M, int N, int K)
{
  __shared__ __attribute__((aligned(16))) u16 As[128 * 32];
  __shared__ __attribute__((aligned(16))) u16 Bs[128 * 32];
  int tid = threadIdx.x, lane = tid & 63, wid = tid >> 6;
  int wm = wid >> 1, wn = wid & 1;
  size_t m0 = (size_t)blockIdx.x * 128, n0 = (size_t)blockIdx.y * 128;

  float4v acc[4][4];
  for (int r = 0; r < 4; r++) for (int c = 0; c < 4; c++) acc[r][c] = (float4v){0.f, 0.f, 0.f, 0.f};

  int srow = tid >> 2;            // 0..63
  int scol = (tid & 3) * 8;       // u16 col offset
  const u16* gA0 = A  + (m0 + srow)      * (size_t)K + scol;
  const u16* gA1 = A  + (m0 + srow + 64) * (size_t)K + scol;
  const u16* gB0 = Bw + (n0 + srow)      * (size_t)K + scol;
  const u16* gB1 = Bw + (n0 + srow + 64) * (size_t)K + scol;

  int l15 = lane & 15, q8 = (lane >> 4) * 8;

  for (int kt = 0; kt < K; kt += 32) {
    uint4 a0 = *(const uint4*)(gA0 + kt);
    uint4 a1 = *(const uint4*)(gA1 + kt);
    uint4 b0 = *(const uint4*)(gB0 + kt);
    uint4 b1 = *(const uint4*)(gB1 + kt);
    __syncthreads();
    ((uint4*)As)[tid]       = a0;
    ((uint4*)As)[tid + 256] = a1;
    ((uint4*)Bs)[tid]       = b0;
    ((uint4*)Bs)[tid + 256] = b1;
    __syncthreads();
    short8 af[4], bfr[4];
    for (int r = 0; r < 4; r++) af[r]  = *(const short8*)&As[(wm * 64 + r * 16 + l15) * 32 + q8];
    for (int c = 0; c < 4; c++) bfr[c] = *(const short8*)&Bs[(wn * 64 + c * 16 + l15) * 32 + q8];
    for (int r = 0; r < 4; r++)
      for (int c = 0; c < 4; c++)
        acc[r][c] = __builtin_amdgcn_mfma_f32_16x16x32_bf16(af[r], bfr[c], acc[r][c], 0, 0, 0);
  }

  int quad = lane >> 4;
  for (int c = 0; c < 4; c++) {
    int n = (int)n0 + wn * 64 + c * 16 + l15;
    float bv = bias ? bias[n] : 0.f;
    for (int r = 0; r < 4; r++) {
      size_t mbase = m0 + wm * 64 + r * 16 + quad * 4;
      for (int t = 0; t < 4; t++)
        C[(mbase + t) * (size_t)N + n] = f2bf(acc[r][c][t] + bv);
    }
  }
}

// ---------- batched dot + square + L1-normalize: adj[g][i][j] ----------
template<int NPAD>
__global__ void __launch_bounds__(256) dot_adj(const u16* __restrict__ QK, float* __restrict__ adj, int n)
{
  constexpr int CT = NPAD / 16;
  __shared__ __attribute__((aligned(16))) u16 As[NPAD * 32];
  __shared__ __attribute__((aligned(16))) u16 Bs[NPAD * 32];
  int g = blockIdx.x, tid = threadIdx.x, lane = tid & 63, wid = tid >> 6;

  float4v acc[CT];
  for (int c = 0; c < CT; c++) acc[c] = (float4v){0.f, 0.f, 0.f, 0.f};

  int row = tid >> 2, kq = tid & 3;
  for (int kt = 0; kt < 768; kt += 32) {
    uint4 va = {0,0,0,0}, vb = {0,0,0,0};
    if (tid < NPAD * 4 && row < n) {
      const u16* base = QK + ((size_t)g * n + row) * 1536 + kt + kq * 8;
      va = *(const uint4*)base;
      vb = *(const uint4*)(base + 768);
    }
    __syncthreads();
    if (tid < NPAD * 4) {
      ((uint4*)As)[tid] = va;
      ((uint4*)Bs)[tid] = vb;
    }
    __syncthreads();
    if (wid < CT) {
      int l15 = lane & 15, q8 = (lane >> 4) * 8;
      short8 a = *(const short8*)&As[(wid * 16 + l15) * 32 + q8];
      for (int ct = 0; ct < CT; ct++) {
        short8 b = *(const short8*)&Bs[(ct * 16 + l15) * 32 + q8];
        acc[ct] = __builtin_amdgcn_mfma_f32_16x16x32_bf16(a, b, acc[ct], 0, 0, 0);
      }
    }
  }

  if (wid < CT) {
    int quad = lane >> 4, l15 = lane & 15;
    float* adjg = adj + (size_t)g * NPAD * NPAD;
    float rs[4];
    for (int r = 0; r < 4; r++) {
      float s = 0.f;
      for (int ct = 0; ct < CT; ct++) { float v = acc[ct][r]; s += v * v; }
      s += __shfl_xor(s, 1); s += __shfl_xor(s, 2); s += __shfl_xor(s, 4); s += __shfl_xor(s, 8);
      rs[r] = 1.0f / fmaxf(s, 1e-12f);
    }
    for (int ct = 0; ct < CT; ct++)
      for (int r = 0; r < 4; r++) {
        float v = acc[ct][r];
        int rrow = wid * 16 + quad * 4 + r, col = ct * 16 + l15;
        adjg[(size_t)rrow * NPAD + col] = v * v * rs[r];
      }
  }
}

// ---------- fused adj@H + LayerNorm + ReLU -> bf16 (ln params fp32) ----------
__global__ void __launch_bounds__(384) adjH_ln(const float* __restrict__ adj, const u16* __restrict__ H,
                                               const float* __restrict__ lng, const float* __restrict__ lnb,
                                               u16* __restrict__ out, int n, int npad, int layer)
{
  __shared__ float adjr[4][64];
  __shared__ float red[6][4][2];
  __shared__ float bc[4][2];
  int g = blockIdx.x, i0 = blockIdx.y * 4;
  int tid = threadIdx.x, wid = tid >> 6, lane = tid & 63;

  for (int idx = tid; idx < 4 * npad; idx += 384) {
    int ii = idx / npad, j = idx - ii * npad;
    adjr[ii][j] = adj[((size_t)g * npad + (i0 + ii)) * npad + j];
  }
  __syncthreads();

  int d0 = tid * 2;
  float a0[4] = {0,0,0,0}, a1[4] = {0,0,0,0};
  const u32* hp = (const u32*)H + (size_t)g * n * 384 + tid;
  for (int j = 0; j < n; j++) {
    u32 u = hp[(size_t)j * 384];
    float h0 = bflo(u), h1 = bfhi(u);
    for (int ii = 0; ii < 4; ii++) { float a = adjr[ii][j]; a0[ii] += a * h0; a1[ii] += a * h1; }
  }

  for (int ii = 0; ii < 4; ii++) {
    float s = a0[ii] + a1[ii];
    float q = a0[ii] * a0[ii] + a1[ii] * a1[ii];
    for (int m = 1; m <= 32; m <<= 1) { s += __shfl_xor(s, m); q += __shfl_xor(q, m); }
    if (lane == 0) { red[wid][ii][0] = s; red[wid][ii][1] = q; }
  }
  __syncthreads();
  if (tid < 4) {
    float s = 0.f, q = 0.f;
    for (int w = 0; w < 6; w++) { s += red[w][tid][0]; q += red[w][tid][1]; }
    float mu = s * (1.f / 768.f);
    float var = q * (1.f / 768.f) - mu * mu;
    bc[tid][0] = mu; bc[tid][1] = rsqrtf(fmaxf(var, 0.f) + 1e-5f);
  }
  __syncthreads();

  float lg0 = lng[layer * 768 + d0], lg1 = lng[layer * 768 + d0 + 1];
  float lb0 = lnb[layer * 768 + d0], lb1 = lnb[layer * 768 + d0 + 1];
  for (int ii = 0; ii < 4; ii++) {
    int i = i0 + ii; if (i >= n) continue;
    float mu = bc[ii][0], rs = bc[ii][1];
    float v0 = fmaxf((a0[ii] - mu) * rs * lg0 + lb0, 0.f);
    float v1 = fmaxf((a1[ii] - mu) * rs * lg1 + lb1, 0.f);
    *(u32*)&out[((size_t)g * n + i) * 768 + d0] = pack2(v0, v1);
  }
}

// ---------- mean over nodes -> bf16 [G][768] ----------
__global__ void __launch_bounds__(384) mean_nodes(const u16* __restrict__ X, u16* __restrict__ out,
                                                  int n, float inv)
{
  int g = blockIdx.x, tid = threadIdx.x;
  const u32* p = (const u32*)X + (size_t)g * n * 384 + tid;
  float s0 = 0.f, s1 = 0.f;
  for (int j = 0; j < n; j++) { u32 u = p[(size_t)j * 384]; s0 += bflo(u); s1 += bfhi(u); }
  ((u32*)out)[(size_t)g * 384 + tid] = pack2(s0 * inv, s1 * inv);
}

// ---------- frame mean (bf16 in) + concat fgs (fp32) -> y fp32 (in d_out) ----------
__global__ void __launch_bounds__(384) frame_mean_concat(const u16* __restrict__ X2f,
                                                         const float* __restrict__ fgs, float* __restrict__ yout)
{
  int b = blockIdx.x, tid = threadIdx.x;
  const u32* p = (const u32*)X2f + (size_t)b * 32 * 384 + tid;
  float s0 = 0.f, s1 = 0.f;
  for (int j = 0; j < 32; j++) { u32 u = p[(size_t)j * 384]; s0 += bflo(u); s1 += bfhi(u); }
  int d0 = tid * 2;
  yout[(size_t)b * 1536 + d0]     = s0 * (1.f / 32.f);
  yout[(size_t)b * 1536 + d0 + 1] = s1 * (1.f / 32.f);
  yout[(size_t)b * 1536 + 768 + d0]     = fgs[(size_t)b * 768 + d0];
  yout[(size_t)b * 1536 + 768 + d0 + 1] = fgs[(size_t)b * 768 + d0 + 1];
}

// ---------- classifier: fc1+relu, wide grid (192 blocks x 4 outputs) ----------
// h[b][o] = relu(y[b] . fc1w[o] + fc1b[o]); y fp32 [16][1536]
__global__ void __launch_bounds__(256) fc1_relu(const float* __restrict__ yout,
                                                const float* __restrict__ fc1w, const float* __restrict__ fc1b,
                                                float* __restrict__ h)
{
  int o = blockIdx.x * 4 + (threadIdx.x >> 6);
  int lane = threadIdx.x & 63;
  float acc[16];
  for (int b = 0; b < 16; b++) acc[b] = 0.f;
  const float4* wr = (const float4*)(fc1w + (size_t)o * 1536);
  for (int k4 = lane; k4 < 384; k4 += 64) {
    float4 wv = wr[k4];
    for (int b = 0; b < 16; b++) {
      float4 yv = ((const float4*)(yout + (size_t)b * 1536))[k4];
      acc[b] += wv.x * yv.x + wv.y * yv.y + wv.z * yv.z + wv.w * yv.w;
    }
  }
  for (int m = 1; m <= 32; m <<= 1)
    for (int b = 0; b < 16; b++) acc[b] += __shfl_xor(acc[b], m);
  if (lane < 16) h[(size_t)lane * 768 + o] = fmaxf(acc[lane] + fc1b[o], 0.f);
}

// ---------- classifier: fc2, wide grid (100 blocks x 4 outputs) ----------
__global__ void __launch_bounds__(256) fc2_out(const float* __restrict__ h,
                                               const float* __restrict__ fc2w, const float* __restrict__ fc2b,
                                               float* __restrict__ logits)
{
  int o = blockIdx.x * 4 + (threadIdx.x >> 6);
  int lane = threadIdx.x & 63;
  float acc[16];
  for (int b = 0; b < 16; b++) acc[b] = 0.f;
  const float4* wr = (const float4*)(fc2w + (size_t)o * 768);
  for (int k4 = lane; k4 < 192; k4 += 64) {
    float4 wv = wr[k4];
    for (int b = 0; b < 16; b++) {
      float4 hv = ((const float4*)(h + (size_t)b * 768))[k4];
      acc[b] += wv.x * hv.x + wv.y * hv.y + wv.z * hv.z + wv.w * hv.w;
    }
  }
  for (int m = 1; m <= 32; m <<= 1)
    for (int b = 0; b < 16; b++) acc[b] += __shfl_xor(acc[b], m);
  if (lane < 16) logits[(size_t)lane * 400 + o] = acc[lane] + fc2b[o];
}

// ---------- launch ----------
extern "C" void kernel_launch(void* const* d_in, const int* in_sizes, int n_in,
                              void* d_out, int out_size, void* d_ws, size_t ws_size,
                              hipStream_t stream) {
  const float* feats = (const float*)d_in[0];
  const float* fgs   = (const float*)d_in[1];
  const float* wq_w  = (const float*)d_in[3];
  const float* wq_b  = (const float*)d_in[4];
  const float* wk_w  = (const float*)d_in[5];
  const float* wk_b  = (const float*)d_in[6];
  const float* gcn_w = (const float*)d_in[7];
  const float* ln_g  = (const float*)d_in[8];
  const float* ln_b  = (const float*)d_in[9];
  const float* fc1_w = (const float*)d_in[10];
  const float* fc1_b = (const float*)d_in[11];
  const float* fc2_w = (const float*)d_in[12];
  const float* fc2_b = (const float*)d_in[13];
  float* out  = (float*)d_out;
  float* yout = out + 16 * 400;               // y region: [16][1536] fp32

  char* ws = (char*)d_ws;
  size_t off = 0;
  auto alloc = [&](size_t b){ size_t r = off; off = (off + b + 255) & ~(size_t)255; return r; };
  // persistent buffers (~47 MB)
  u16*  Fb     = (u16*) (ws + alloc((size_t)25600 * 768 * 2));   // feats as bf16
  u16*  Wqk    = (u16*) (ws + alloc((size_t)1536 * 768 * 2));
  u16*  gcnT   = (u16*) (ws + alloc((size_t)2 * 768 * 768 * 2));
  float* biasQK= (float*)(ws + alloc((size_t)1536 * 4));
  u16*  Xf     = (u16*) (ws + alloc((size_t)512 * 768 * 2));
  u16*  QKf    = (u16*) (ws + alloc((size_t)512 * 1536 * 2));
  u16*  Hf     = (u16*) (ws + alloc((size_t)512 * 768 * 2));
  u16*  X1f    = (u16*) (ws + alloc((size_t)512 * 768 * 2));
  u16*  X2f    = (u16*) (ws + alloc((size_t)512 * 768 * 2));
  float* adjF  = (float*)(ws + alloc((size_t)16 * 32 * 32 * 4));
  float* hbuf  = (float*)(ws + alloc((size_t)16 * 768 * 4));
  size_t base = off;

  // object-level chunk size by ws budget (ws_size constant -> graph-safe)
  auto need = [&](int GC){ return base + (size_t)GC * 50 * 1536 * 2 + 512 + (size_t)GC * 64 * 64 * 4 + 512; };
  int GC = 64;
  if (need(512) <= ws_size) GC = 512;
  else if (need(256) <= ws_size) GC = 256;
  else if (need(128) <= ws_size) GC = 128;
  int R = GC * 50;
  size_t off2 = base;
  auto alloc2 = [&](size_t b){ size_t r = off2; off2 = (off2 + b + 255) & ~(size_t)255; return r; };
  u16*  QKc  = (u16*) (ws + alloc2((size_t)R * 1536 * 2));
  float* adjO = (float*)(ws + alloc2((size_t)GC * 64 * 64 * 4));
  u16* Hc  = QKc;                        // [R][768] (QK dead after dot_adj)
  u16* X1c = QKc + (size_t)R * 768;
  u16* H2c = QKc;
  u16* X2c = QKc + (size_t)R * 768;

  // prep
  f32_to_bf16<<<4800, 256, 0, stream>>>(feats, Fb, 25600 * 768 / 4);
  prep_qkw<<<288, 256, 0, stream>>>(wq_w, wk_w, wq_b, wk_b, Wqk, biasQK);
  prep_gcnT<<<dim3(24, 24, 2), dim3(32, 8), 0, stream>>>(gcn_w, gcnT);

  // ---- object-level graph (512 graphs of n=50), chunked ----
  int nchunks = 512 / GC;
  for (int c = 0; c < nchunks; c++) {
    const u16* fc = Fb + (size_t)c * GC * 50 * 768;
    gemm_bt<<<dim3(R / 128, 12), 256, 0, stream>>>(fc, Wqk, biasQK, QKc, R, 1536, 768);
    dot_adj<64><<<GC, 256, 0, stream>>>(QKc, adjO, 50);
    gemm_bt<<<dim3(R / 128, 6), 256, 0, stream>>>(fc, gcnT, nullptr, Hc, R, 768, 768);
    adjH_ln<<<dim3(GC, 13), 384, 0, stream>>>(adjO, Hc, ln_g, ln_b, X1c, 50, 64, 0);
    gemm_bt<<<dim3(R / 128, 6), 256, 0, stream>>>(X1c, gcnT + (size_t)768 * 768, nullptr, H2c, R, 768, 768);
    adjH_ln<<<dim3(GC, 13), 384, 0, stream>>>(adjO, H2c, ln_g, ln_b, X2c, 50, 64, 1);
    mean_nodes<<<GC, 384, 0, stream>>>(X2c, Xf + (size_t)c * GC * 768, 50, 1.f / 50.f);
  }

  // ---- frame-level graph (16 graphs of n=32) ----
  gemm_bt<<<dim3(4, 12), 256, 0, stream>>>(Xf, Wqk, biasQK, QKf, 512, 1536, 768);
  dot_adj<32><<<16, 256, 0, stream>>>(QKf, adjF, 32);
  gemm_bt<<<dim3(4, 6), 256, 0, stream>>>(Xf, gcnT, nullptr, Hf, 512, 768, 768);
  adjH_ln<<<dim3(16, 8), 384, 0, stream>>>(adjF, Hf, ln_g, ln_b, X1f, 32, 32, 0);
  gemm_bt<<<dim3(4, 6), 256, 0, stream>>>(X1f, gcnT + (size_t)768 * 768, nullptr, Hf, 512, 768, 768);
  adjH_ln<<<dim3(16, 8), 384, 0, stream>>>(adjF, Hf, ln_g, ln_b, X2f, 32, 32, 1);

  // ---- head ----
  frame_mean_concat<<<16, 384, 0, stream>>>(X2f, fgs, yout);
  fc1_relu<<<192, 256, 0, stream>>>(yout, fc1_w, fc1_b, hbuf);
  fc2_out<<<100, 256, 0, stream>>>(hbuf, fc2_w, fc2_b, out);
}